// Round 1
// baseline (124.039 us; speedup 1.0000x reference)
//
#include <hip/hip_runtime.h>

// STDP Linear layer: B=64, IN=4096, OUT=1024, all fp32.
// Outputs concatenated in d_out: spikes[64,1024] | mem[64,1024] |
// w_new[1024,4096] | tp[64,4096] | tq[64,1024]
//
// Kernel graph:  A(gemm1 splitK, partials into w_new region) -> B(reduce+LIF+tq)
//                D(tp elementwise, independent)              -> C(w_new rank-64 update)

#define B_    64
#define IN_   4096
#define OUT_  1024
#define SPLITS 32
#define KC    128   // 4096 / 32

static constexpr int OFF_SPIKES = 0;
static constexpr int OFF_MEM    = B_ * OUT_;               // 65536
static constexpr int OFF_W      = 2 * B_ * OUT_;           // 131072
static constexpr int OFF_TP     = OFF_W + OUT_ * IN_;      // 4325376
static constexpr int OFF_TQ     = OFF_TP + B_ * IN_;       // 4587520

// ---------------------------------------------------------------------------
// A: weighted partial GEMM.  grid (16 n-tiles, 32 k-splits), 256 threads.
// Wave w of block handles 16 output neurons n0..n0+15 for ALL 64 batches
// (lane == batch).  weight[n,k] is wave-uniform -> scalar loads; in_spikes
// row is lane-private (register resident, float4).
// Partials written as part[ks][b][n] (coalesced) via a swizzled LDS transpose.
// ---------------------------------------------------------------------------
__global__ __launch_bounds__(256) void k_gemm1(const float* __restrict__ A,
                                               const float* __restrict__ Wt,
                                               float* __restrict__ part) {
  const int nb   = blockIdx.x;           // 0..15
  const int ks   = blockIdx.y;           // 0..31
  const int w    = threadIdx.x >> 6;     // wave id 0..3
  const int lane = threadIdx.x & 63;     // batch
  const int n0   = __builtin_amdgcn_readfirstlane(nb * 64 + w * 16);
  const int k0   = ks * KC;

  const float* a  = A  + (size_t)lane * IN_ + k0;
  const float* wp = Wt + (size_t)n0   * IN_ + k0;

  float acc[16];
#pragma unroll
  for (int j = 0; j < 16; ++j) acc[j] = 0.f;

#pragma unroll 2
  for (int k = 0; k < KC; k += 4) {
    const float4 av = *reinterpret_cast<const float4*>(a + k);
#pragma unroll
    for (int j = 0; j < 16; ++j) {
      const float* wr = wp + j * IN_ + k;   // wave-uniform address -> s_load
      float t0 = fmaf(av.x, wr[0], acc[j]);
      t0       = fmaf(av.y, wr[1], t0);
      t0       = fmaf(av.z, wr[2], t0);
      acc[j]   = fmaf(av.w, wr[3], t0);
    }
  }

  // transpose [lane=b][n] tile through LDS so the global write is coalesced.
  // XOR-swizzle columns to break the 8-way bank conflict of stride-68 rows.
  __shared__ float tile[64][68];
#pragma unroll
  for (int j = 0; j < 16; ++j) {
    const int c = (w * 16 + j) ^ ((lane & 7) << 2);
    tile[lane][c] = acc[j];
  }
  __syncthreads();

  const int c4 = threadIdx.x & 15;   // 16 float4 per row
  const int r0 = threadIdx.x >> 4;   // 16 row-groups
#pragma unroll
  for (int i = 0; i < 4; ++i) {
    const int b = r0 + i * 16;
    const float4 v = *reinterpret_cast<const float4*>(
        &tile[b][(c4 * 4) ^ ((b & 7) << 2)]);
    *reinterpret_cast<float4*>(
        part + ((size_t)(ks * 64 + b)) * OUT_ + nb * 64 + c4 * 4) = v;
  }
}

// ---------------------------------------------------------------------------
// B: reduce 32 partials (deterministic order) + LIF + tq.  65536 threads.
// ---------------------------------------------------------------------------
__global__ __launch_bounds__(256) void k_lif(const float* __restrict__ part,
                                             const float* __restrict__ membrane,
                                             const float* __restrict__ trace_post,
                                             float* __restrict__ out) {
  const int t = blockIdx.x * 256 + threadIdx.x;   // 0..65535
  const int b = t >> 10;
  const int n = t & (OUT_ - 1);

  float s0 = 0.f, s1 = 0.f, s2 = 0.f, s3 = 0.f;
#pragma unroll
  for (int ks = 0; ks < SPLITS; ks += 4) {
    s0 += part[((size_t)((ks + 0) * B_ + b)) * OUT_ + n];
    s1 += part[((size_t)((ks + 1) * B_ + b)) * OUT_ + n];
    s2 += part[((size_t)((ks + 2) * B_ + b)) * OUT_ + n];
    s3 += part[((size_t)((ks + 3) * B_ + b)) * OUT_ + n];
  }
  const float weighted = (s0 + s1) + (s2 + s3);

  const float mem   = fmaf(membrane[t], 0.98f, weighted);
  const float spike = (mem > 0.4f) ? 1.0f : 0.0f;
  const float memo  = (spike > 0.0f) ? 0.0f : mem;
  float tq = fmaf(trace_post[n], 0.85f, spike);
  tq = fminf(fmaxf(tq, 0.0f), 1.0f);

  out[OFF_SPIKES + t] = spike;
  out[OFF_MEM    + t] = memo;
  out[OFF_TQ     + t] = tq;
}

// ---------------------------------------------------------------------------
// D: tp = clip(trace_pre*0.85 + in_spikes, 0, 1).  float4, 65536 threads.
// ---------------------------------------------------------------------------
__global__ __launch_bounds__(256) void k_tp(const float* __restrict__ in_spikes,
                                            const float* __restrict__ trace_pre,
                                            float* __restrict__ out) {
  const int t  = blockIdx.x * 256 + threadIdx.x;   // float4 index
  const int i4 = t & (IN_ / 4 - 1);
  const float4 x  = reinterpret_cast<const float4*>(in_spikes)[t];
  const float4 tr = reinterpret_cast<const float4*>(trace_pre)[i4];
  float4 r;
  r.x = fminf(fmaxf(fmaf(tr.x, 0.85f, x.x), 0.0f), 1.0f);
  r.y = fminf(fmaxf(fmaf(tr.y, 0.85f, x.y), 0.0f), 1.0f);
  r.z = fminf(fmaxf(fmaf(tr.z, 0.85f, x.z), 0.0f), 1.0f);
  r.w = fminf(fmaxf(fmaf(tr.w, 0.85f, x.w), 0.0f), 1.0f);
  reinterpret_cast<float4*>(out + OFF_TP)[t] = r;
}

// ---------------------------------------------------------------------------
// C: w_new = clip(weight + 0.001 * tq^T tp, -0.1, 0.5).
// grid (64 i-tiles, 16 o-tiles), 256 threads, 64x64 tile, 16 acc/thread.
// Memory-bound: weight in + w_new out stream; K=64 dot from LDS.
// ---------------------------------------------------------------------------
__global__ __launch_bounds__(256) void k_wnew(const float* __restrict__ weight,
                                              const float* __restrict__ tp,
                                              const float* __restrict__ tq,
                                              float* __restrict__ wout) {
  const int i0 = blockIdx.x * 64;
  const int o0 = blockIdx.y * 64;

  __shared__ float tpl[64][68];
  __shared__ float tql[64][68];
  {
    const int c4 = threadIdx.x & 15;
    const int rr = threadIdx.x >> 4;
#pragma unroll
    for (int r = 0; r < 4; ++r) {
      const int b = rr + r * 16;
      *reinterpret_cast<float4*>(&tpl[b][c4 * 4]) =
          *reinterpret_cast<const float4*>(tp + (size_t)b * IN_  + i0 + c4 * 4);
      *reinterpret_cast<float4*>(&tql[b][c4 * 4]) =
          *reinterpret_cast<const float4*>(tq + (size_t)b * OUT_ + o0 + c4 * 4);
    }
  }
  __syncthreads();

  const int il = threadIdx.x & 15;   // i-group: i = i0 + il*4 + v
  const int ol = threadIdx.x >> 4;   // o-group: o = o0 + ol*4 + u

  float acc[4][4];
#pragma unroll
  for (int u = 0; u < 4; ++u)
#pragma unroll
    for (int v = 0; v < 4; ++v) acc[u][v] = 0.f;

#pragma unroll 4
  for (int b = 0; b < 64; ++b) {
    const float4 tpv = *reinterpret_cast<const float4*>(&tpl[b][il * 4]);
    const float4 tqv = *reinterpret_cast<const float4*>(&tql[b][ol * 4]);
    const float tp4[4] = {tpv.x, tpv.y, tpv.z, tpv.w};
    const float tq4[4] = {tqv.x, tqv.y, tqv.z, tqv.w};
#pragma unroll
    for (int u = 0; u < 4; ++u)
#pragma unroll
      for (int v = 0; v < 4; ++v)
        acc[u][v] = fmaf(tq4[u], tp4[v], acc[u][v]);
  }

  const float cdw = (float)(0.005 - 0.004);   // A_POS - A_NEG, matches ref
#pragma unroll
  for (int u = 0; u < 4; ++u) {
    const int o = o0 + ol * 4 + u;
    const float4 wv = *reinterpret_cast<const float4*>(
        weight + (size_t)o * IN_ + i0 + il * 4);
    float4 r;
    r.x = fminf(fmaxf(fmaf(cdw, acc[u][0], wv.x), -0.1f), 0.5f);
    r.y = fminf(fmaxf(fmaf(cdw, acc[u][1], wv.y), -0.1f), 0.5f);
    r.z = fminf(fmaxf(fmaf(cdw, acc[u][2], wv.z), -0.1f), 0.5f);
    r.w = fminf(fmaxf(fmaf(cdw, acc[u][3], wv.w), -0.1f), 0.5f);
    *reinterpret_cast<float4*>(wout + (size_t)o * IN_ + i0 + il * 4) = r;
  }
}

// ---------------------------------------------------------------------------
extern "C" void kernel_launch(void* const* d_in, const int* in_sizes, int n_in,
                              void* d_out, int out_size, void* d_ws, size_t ws_size,
                              hipStream_t stream) {
  const float* in_spikes  = (const float*)d_in[0];
  const float* weight     = (const float*)d_in[1];
  const float* membrane   = (const float*)d_in[2];
  const float* trace_pre  = (const float*)d_in[3];
  const float* trace_post = (const float*)d_in[4];
  float* out = (float*)d_out;

  // Split-K partials live inside the w_new output region (8 MB of its 16 MB);
  // consumed by k_lif before k_wnew overwrites the region with the real w_new.
  float* part = out + OFF_W;

  k_gemm1<<<dim3(16, SPLITS), 256, 0, stream>>>(in_spikes, weight, part);
  k_tp   <<<dim3(256),        256, 0, stream>>>(in_spikes, trace_pre, out);
  k_lif  <<<dim3(256),        256, 0, stream>>>(part, membrane, trace_post, out);
  k_wnew <<<dim3(64, 16),     256, 0, stream>>>(weight, out + OFF_TP,
                                                out + OFF_TQ, out + OFF_W);
}

// Round 3
// 98.503 us; speedup vs baseline: 1.2592x; 1.2592x over previous
//
#include <hip/hip_runtime.h>

// STDP Linear layer: B=64, IN=4096, OUT=1024, all fp32.
// Outputs concatenated in d_out: spikes[64,1024] | mem[64,1024] |
// w_new[1024,4096] | tp[64,4096] | tq[64,1024]
//
// Kernel graph:  A(gemm1 splitK, partials into w_new region) -> B(reduce+LIF+tq)
//                D(tp elementwise, independent)              -> C(w_new rank-64 update)

#define B_    64
#define IN_   4096
#define OUT_  1024
#define SPLITS 32
#define KC    128   // k-range per block = 4096 / 32
#define BK    64    // k-chunk staged in LDS

static constexpr int OFF_SPIKES = 0;
static constexpr int OFF_MEM    = B_ * OUT_;               // 65536
static constexpr int OFF_W      = 2 * B_ * OUT_;           // 131072
static constexpr int OFF_TP     = OFF_W + OUT_ * IN_;      // 4325376
static constexpr int OFF_TQ     = OFF_TP + B_ * IN_;       // 4587520

// ---------------------------------------------------------------------------
// A: weighted partial GEMM, LDS-tiled.  grid (16 n-tiles, 32 k-splits), 256 thr.
// Tile: 64 batches x 64 neurons, k-chunks of 64.  Both tiles staged K-MAJOR
// (transpose on stage) with XOR swizzle col ^= 2*(k>>2):
//   - stride 64 floats (no pad) keeps ds_read_b128 16B-aligned
//   - write banks: (col^2i)&31 -> 2-way max (free);  reads: broadcast / 2-way
//   - bit-1 of the swizzle permutes elements WITHIN the float4; the k-loop is
//     fully unrolled so the permutation is a compile-time register rename.
// Thread (bu = tid>>4, nv = tid&15) owns acc[4][4] = batches bu*4+u, neurons
// nv*4+v  ->  16 FMA per 2 ds_read_b128: VALU-bound by design.
// ---------------------------------------------------------------------------
__global__ __launch_bounds__(256) void k_gemm1(const float* __restrict__ A,
                                               const float* __restrict__ Wt,
                                               float* __restrict__ part) {
  const int nb = blockIdx.x;           // 0..15  (64-neuron tile)
  const int ks = blockIdx.y;           // 0..31  (128-k split)
  const int t  = threadIdx.x;

  __shared__ float At[BK][64];   // k-major: At[k][b ^ swz(k)]
  __shared__ float Wn[BK][64];   // k-major: Wn[k][n ^ swz(k)]

  const int col4 = t & 15;             // k-quad within chunk (staging)
  const int rowg = t >> 4;             // row group 0..15 (staging)
  const int bu   = t >> 4;             // batch group (compute)
  const int nv   = t & 15;             // neuron group (compute)

  float acc[4][4];
#pragma unroll
  for (int u = 0; u < 4; ++u)
#pragma unroll
    for (int v = 0; v < 4; ++v) acc[u][v] = 0.f;

#pragma unroll
  for (int c = 0; c < KC / BK; ++c) {
    const int k0 = ks * KC + c * BK;

    // ---- load both 64x64 tiles into registers (coalesced float4) ----
    float4 av[4], wv[4];
#pragma unroll
    for (int p = 0; p < 4; ++p) {
      const int r = rowg + p * 16;
      av[p] = *reinterpret_cast<const float4*>(A  + (size_t)r * IN_ + k0 + col4 * 4);
      wv[p] = *reinterpret_cast<const float4*>(Wt + (size_t)(nb * 64 + r) * IN_ + k0 + col4 * 4);
    }

    if (c) __syncthreads();            // previous chunk's compute done

    // ---- transpose into k-major LDS with XOR swizzle (k-quad = col4) ----
    const int sw = 2 * col4;           // swizzle for k rows 4*col4 .. +3
#pragma unroll
    for (int p = 0; p < 4; ++p) {
      const int r = rowg + p * 16;
      const int cA = r ^ sw;
      At[col4 * 4 + 0][cA] = av[p].x;
      At[col4 * 4 + 1][cA] = av[p].y;
      At[col4 * 4 + 2][cA] = av[p].z;
      At[col4 * 4 + 3][cA] = av[p].w;
      Wn[col4 * 4 + 0][cA] = wv[p].x;
      Wn[col4 * 4 + 1][cA] = wv[p].y;
      Wn[col4 * 4 + 2][cA] = wv[p].z;
      Wn[col4 * 4 + 3][cA] = wv[p].w;
    }
    __syncthreads();

    // ---- compute: fully unrolled so swizzle perm is static ----
#pragma unroll
    for (int kq = 0; kq < BK / 4; ++kq) {
      const int sH = (2 * kq) & 28;    // high bits of swizzle -> address XOR
      const int tt = (2 * kq) & 2;     // bit1 -> element pair-swap (static)
#pragma unroll
      for (int m = 0; m < 4; ++m) {
        const int kk = kq * 4 + m;
        const float4 a4 = *reinterpret_cast<const float4*>(&At[kk][(bu * 4) ^ sH]);
        const float4 w4 = *reinterpret_cast<const float4*>(&Wn[kk][(nv * 4) ^ sH]);
        const float aa[4] = {a4.x, a4.y, a4.z, a4.w};
        const float ww[4] = {w4.x, w4.y, w4.z, w4.w};
#pragma unroll
        for (int u = 0; u < 4; ++u)
#pragma unroll
          for (int v = 0; v < 4; ++v)
            acc[u][v] = fmaf(aa[u ^ (tt ? 2 : 0)], ww[v ^ (tt ? 2 : 0)], acc[u][v]);
      }
    }
  }

  // ---- write partials: part[ks][b][n], float4, coalesced ----
#pragma unroll
  for (int u = 0; u < 4; ++u) {
    const int b = bu * 4 + u;
    float4 r;
    r.x = acc[u][0]; r.y = acc[u][1]; r.z = acc[u][2]; r.w = acc[u][3];
    *reinterpret_cast<float4*>(
        part + ((size_t)(ks * 64 + b)) * OUT_ + nb * 64 + nv * 4) = r;
  }
}

// ---------------------------------------------------------------------------
// B: reduce 32 partials (deterministic order) + LIF + tq.  65536 threads.
// ---------------------------------------------------------------------------
__global__ __launch_bounds__(256) void k_lif(const float* __restrict__ part,
                                             const float* __restrict__ membrane,
                                             const float* __restrict__ trace_post,
                                             float* __restrict__ out) {
  const int t = blockIdx.x * 256 + threadIdx.x;   // 0..65535
  const int b = t >> 10;
  const int n = t & (OUT_ - 1);

  float s0 = 0.f, s1 = 0.f, s2 = 0.f, s3 = 0.f;
#pragma unroll
  for (int ks = 0; ks < SPLITS; ks += 4) {
    s0 += part[((size_t)((ks + 0) * B_ + b)) * OUT_ + n];
    s1 += part[((size_t)((ks + 1) * B_ + b)) * OUT_ + n];
    s2 += part[((size_t)((ks + 2) * B_ + b)) * OUT_ + n];
    s3 += part[((size_t)((ks + 3) * B_ + b)) * OUT_ + n];
  }
  const float weighted = (s0 + s1) + (s2 + s3);

  const float mem   = fmaf(membrane[t], 0.98f, weighted);
  const float spike = (mem > 0.4f) ? 1.0f : 0.0f;
  const float memo  = (spike > 0.0f) ? 0.0f : mem;
  float tq = fmaf(trace_post[n], 0.85f, spike);
  tq = fminf(fmaxf(tq, 0.0f), 1.0f);

  out[OFF_SPIKES + t] = spike;
  out[OFF_MEM    + t] = memo;
  out[OFF_TQ     + t] = tq;
}

// ---------------------------------------------------------------------------
// D: tp = clip(trace_pre*0.85 + in_spikes, 0, 1).  float4, 65536 threads.
// ---------------------------------------------------------------------------
__global__ __launch_bounds__(256) void k_tp(const float* __restrict__ in_spikes,
                                            const float* __restrict__ trace_pre,
                                            float* __restrict__ out) {
  const int t  = blockIdx.x * 256 + threadIdx.x;   // float4 index
  const int i4 = t & (IN_ / 4 - 1);
  const float4 x  = reinterpret_cast<const float4*>(in_spikes)[t];
  const float4 tr = reinterpret_cast<const float4*>(trace_pre)[i4];
  float4 r;
  r.x = fminf(fmaxf(fmaf(tr.x, 0.85f, x.x), 0.0f), 1.0f);
  r.y = fminf(fmaxf(fmaf(tr.y, 0.85f, x.y), 0.0f), 1.0f);
  r.z = fminf(fmaxf(fmaf(tr.z, 0.85f, x.z), 0.0f), 1.0f);
  r.w = fminf(fmaxf(fmaf(tr.w, 0.85f, x.w), 0.0f), 1.0f);
  reinterpret_cast<float4*>(out + OFF_TP)[t] = r;
}

// ---------------------------------------------------------------------------
// C: w_new = clip(weight + 0.001 * tq^T tp, -0.1, 0.5).
// grid (64 i-tiles, 16 o-tiles), 256 threads, 64x64 tile, 16 acc/thread.
// Memory-bound: weight in + w_new out stream; K=64 dot from LDS.
// ---------------------------------------------------------------------------
__global__ __launch_bounds__(256) void k_wnew(const float* __restrict__ weight,
                                              const float* __restrict__ tp,
                                              const float* __restrict__ tq,
                                              float* __restrict__ wout) {
  const int i0 = blockIdx.x * 64;
  const int o0 = blockIdx.y * 64;

  __shared__ float tpl[64][68];
  __shared__ float tql[64][68];
  {
    const int c4 = threadIdx.x & 15;
    const int rr = threadIdx.x >> 4;
#pragma unroll
    for (int r = 0; r < 4; ++r) {
      const int b = rr + r * 16;
      *reinterpret_cast<float4*>(&tpl[b][c4 * 4]) =
          *reinterpret_cast<const float4*>(tp + (size_t)b * IN_  + i0 + c4 * 4);
      *reinterpret_cast<float4*>(&tql[b][c4 * 4]) =
          *reinterpret_cast<const float4*>(tq + (size_t)b * OUT_ + o0 + c4 * 4);
    }
  }
  __syncthreads();

  const int il = threadIdx.x & 15;   // i-group: i = i0 + il*4 + v
  const int ol = threadIdx.x >> 4;   // o-group: o = o0 + ol*4 + u

  float acc[4][4];
#pragma unroll
  for (int u = 0; u < 4; ++u)
#pragma unroll
    for (int v = 0; v < 4; ++v) acc[u][v] = 0.f;

#pragma unroll 4
  for (int b = 0; b < 64; ++b) {
    const float4 tpv = *reinterpret_cast<const float4*>(&tpl[b][il * 4]);
    const float4 tqv = *reinterpret_cast<const float4*>(&tql[b][ol * 4]);
    const float tp4[4] = {tpv.x, tpv.y, tpv.z, tpv.w};
    const float tq4[4] = {tqv.x, tqv.y, tqv.z, tqv.w};
#pragma unroll
    for (int u = 0; u < 4; ++u)
#pragma unroll
      for (int v = 0; v < 4; ++v)
        acc[u][v] = fmaf(tq4[u], tp4[v], acc[u][v]);
  }

  const float cdw = (float)(0.005 - 0.004);   // A_POS - A_NEG, matches ref
#pragma unroll
  for (int u = 0; u < 4; ++u) {
    const int o = o0 + ol * 4 + u;
    const float4 wv = *reinterpret_cast<const float4*>(
        weight + (size_t)o * IN_ + i0 + il * 4);
    float4 r;
    r.x = fminf(fmaxf(fmaf(cdw, acc[u][0], wv.x), -0.1f), 0.5f);
    r.y = fminf(fmaxf(fmaf(cdw, acc[u][1], wv.y), -0.1f), 0.5f);
    r.z = fminf(fmaxf(fmaf(cdw, acc[u][2], wv.z), -0.1f), 0.5f);
    r.w = fminf(fmaxf(fmaf(cdw, acc[u][3], wv.w), -0.1f), 0.5f);
    *reinterpret_cast<float4*>(wout + (size_t)o * IN_ + i0 + il * 4) = r;
  }
}

// ---------------------------------------------------------------------------
extern "C" void kernel_launch(void* const* d_in, const int* in_sizes, int n_in,
                              void* d_out, int out_size, void* d_ws, size_t ws_size,
                              hipStream_t stream) {
  const float* in_spikes  = (const float*)d_in[0];
  const float* weight     = (const float*)d_in[1];
  const float* membrane   = (const float*)d_in[2];
  const float* trace_pre  = (const float*)d_in[3];
  const float* trace_post = (const float*)d_in[4];
  float* out = (float*)d_out;

  // Split-K partials live inside the w_new output region (8 MB of its 16 MB);
  // consumed by k_lif before k_wnew overwrites the region with the real w_new.
  float* part = out + OFF_W;

  k_gemm1<<<dim3(16, SPLITS), 256, 0, stream>>>(in_spikes, weight, part);
  k_tp   <<<dim3(256),        256, 0, stream>>>(in_spikes, trace_pre, out);
  k_lif  <<<dim3(256),        256, 0, stream>>>(part, membrane, trace_post, out);
  k_wnew <<<dim3(64, 16),     256, 0, stream>>>(weight, out + OFF_TP,
                                                out + OFF_TQ, out + OFF_W);
}